// Round 1
// baseline (11657.333 us; speedup 1.0000x reference)
//
#include <hip/hip_runtime.h>

#define T_LEN 8192
#define N_NODES 33
#define N_EDGES 64
#define DIM_IN 3
#define D_H 64
#define D_LSTM 128
#define N_CLS 5
#define TB 4   // timesteps per block in kernel 1

// ---------------------------------------------------------------------------
// Kernel 1: graph conv x2 + relu + mean over nodes + input-side LSTM projection
// Writes A[t][o] = seq_t @ W_ih.T + b_ih + b_hh   (T x 512)
// One block = 64 threads (1 wave) handles TB consecutive timesteps.
// ---------------------------------------------------------------------------
__global__ __launch_bounds__(64, 2) void gnn_proj_kernel(
    const float* __restrict__ x,        // (T,33,3)
    const int*   __restrict__ esrc,     // (64,)
    const int*   __restrict__ edst,     // (64,)
    const float* __restrict__ W_rel1,   // (64,3)
    const float* __restrict__ b_rel1,   // (64,)
    const float* __restrict__ W_root1,  // (64,3)
    const float* __restrict__ W_rel2,   // (64,64)
    const float* __restrict__ b_rel2,   // (64,)
    const float* __restrict__ W_root2,  // (64,64)
    const float* __restrict__ W_ih,     // (512,64)
    const float* __restrict__ b_ih,     // (512,)
    const float* __restrict__ b_hh,     // (512,)
    float* __restrict__ A)              // (T,512)  [workspace]
{
    const int t0 = blockIdx.x * TB;
    const int j  = threadIdx.x;   // 0..63, owns feature dim j

    __shared__ __align__(16) float x_s[N_NODES][DIM_IN];
    __shared__ __align__(16) float agg1[N_NODES][DIM_IN];
    __shared__ __align__(16) float h1[N_NODES][D_H];
    __shared__ __align__(16) float agg2[N_NODES][D_H];
    __shared__ __align__(16) float seq_s[TB][D_H];
    __shared__ int es[N_EDGES], ed[N_EDGES];

    es[j] = esrc[j];
    ed[j] = edst[j];

    // per-thread weights for layer 1 (row j)
    const float wr1_0 = W_rel1[j*3+0], wr1_1 = W_rel1[j*3+1], wr1_2 = W_rel1[j*3+2];
    const float wt1_0 = W_root1[j*3+0], wt1_1 = W_root1[j*3+1], wt1_2 = W_root1[j*3+2];
    const float br1 = b_rel1[j];
    const float br2 = b_rel2[j];

    // per-thread weights for layer 2 (row j) held in VGPRs
    float wr2[D_H], wt2[D_H];
    #pragma unroll
    for (int k = 0; k < D_H; ++k) {
        wr2[k] = W_rel2[j*D_H + k];
        wt2[k] = W_root2[j*D_H + k];
    }

    for (int tt = 0; tt < TB; ++tt) {
        const int t = t0 + tt;
        __syncthreads();   // protect LDS from previous iteration's readers

        // ---- load x_t (99 floats) ----
        const float* xt = x + (size_t)t * (N_NODES * DIM_IN);
        for (int i = j; i < N_NODES * DIM_IN; i += 64) x_s[0][i] = xt[i];
        __syncthreads();

        // ---- conv1 scatter-aggregate (per destination node, no atomics) ----
        if (j < N_NODES) {
            float a0 = 0.f, a1 = 0.f, a2 = 0.f;
            for (int e = 0; e < N_EDGES; ++e) {
                if (ed[e] == j) {
                    a0 += x_s[es[e]][0];
                    a1 += x_s[es[e]][1];
                    a2 += x_s[es[e]][2];
                }
            }
            agg1[j][0] = a0; agg1[j][1] = a1; agg1[j][2] = a2;
        }
        __syncthreads();

        // ---- h1[n][j] = agg1[n]·W_rel1[j] + b_rel1[j] + x[n]·W_root1[j]; zero agg2 ----
        for (int n = 0; n < N_NODES; ++n) {
            float v = br1
                + agg1[n][0]*wr1_0 + agg1[n][1]*wr1_1 + agg1[n][2]*wr1_2
                + x_s[n][0]*wt1_0  + x_s[n][1]*wt1_1  + x_s[n][2]*wt1_2;
            h1[n][j]  = v;
            agg2[n][j] = 0.f;
        }
        __syncthreads();

        // ---- conv2 scatter: thread j owns column j, fixed edge order ----
        for (int e = 0; e < N_EDGES; ++e) {
            agg2[ed[e]][j] += h1[es[e]][j];
        }
        __syncthreads();

        // ---- h2[n][j] -> relu -> mean over n ----
        float seqv = 0.f;
        for (int n = 0; n < N_NODES; ++n) {
            const float4* ag4 = (const float4*)agg2[n];
            const float4* h4  = (const float4*)h1[n];
            float acc0 = br2, acc1 = 0.f, acc2 = 0.f, acc3 = 0.f;
            #pragma unroll
            for (int k4 = 0; k4 < D_H/4; ++k4) {
                float4 av = ag4[k4];
                float4 hv = h4[k4];
                acc0 += av.x * wr2[4*k4+0] + hv.x * wt2[4*k4+0];
                acc1 += av.y * wr2[4*k4+1] + hv.y * wt2[4*k4+1];
                acc2 += av.z * wr2[4*k4+2] + hv.z * wt2[4*k4+2];
                acc3 += av.w * wr2[4*k4+3] + hv.w * wt2[4*k4+3];
            }
            float acc = (acc0 + acc1) + (acc2 + acc3);
            seqv += fmaxf(acc, 0.f);
        }
        seq_s[tt][j] = seqv * (1.0f / 33.0f);
    }
    __syncthreads();

    // ---- A[t][o] = b_ih[o]+b_hh[o] + seq_t · W_ih[o]  (8 outputs / thread) ----
    #pragma unroll
    for (int m = 0; m < 8; ++m) {
        const int o = m * 64 + j;
        const float bias = b_ih[o] + b_hh[o];
        const float4* w4 = (const float4*)(W_ih + (size_t)o * D_H);
        float acc[TB];
        #pragma unroll
        for (int tt = 0; tt < TB; ++tt) acc[tt] = bias;
        #pragma unroll
        for (int k4 = 0; k4 < D_H/4; ++k4) {
            float4 wv = w4[k4];
            #pragma unroll
            for (int tt = 0; tt < TB; ++tt) {
                const float4* s4 = (const float4*)seq_s[tt];
                float4 sv = s4[k4];
                acc[tt] += sv.x*wv.x + sv.y*wv.y + sv.z*wv.z + sv.w*wv.w;
            }
        }
        #pragma unroll
        for (int tt = 0; tt < TB; ++tt) {
            A[(size_t)(t0 + tt) * 512 + o] = acc[tt];
        }
    }
}

// ---------------------------------------------------------------------------
// Kernel 2: sequential LSTM over T steps, single block (1 CU), 512 threads.
// Thread j owns gate row j of W_hh (128 VGPRs). Threads 0..127 own c_j / h_j.
// Fused final FC at the end.
// ---------------------------------------------------------------------------
__device__ __forceinline__ float sigmoid_f(float v) {
    return 1.0f / (1.0f + __expf(-v));
}
__device__ __forceinline__ float tanh_f(float v) {
    // safe at both extremes: exp(2v)->inf => 1 ; ->0 => -1
    return 1.0f - 2.0f / (1.0f + __expf(2.0f * v));
}

__global__ __launch_bounds__(512, 2) void lstm_kernel(
    const float* __restrict__ A,      // (T,512)
    const float* __restrict__ W_hh,   // (512,128)
    const float* __restrict__ W_fc,   // (5,128)
    const float* __restrict__ b_fc,   // (5,)
    float* __restrict__ out)          // (5,)
{
    const int j = threadIdx.x;  // 0..511, gate row

    __shared__ __align__(16) float h_s[D_LSTM];
    __shared__ float gates_s[4 * D_LSTM];

    // W_hh row j in registers
    float w[D_LSTM];
    #pragma unroll
    for (int k = 0; k < D_LSTM; ++k) w[k] = W_hh[(size_t)j * D_LSTM + k];

    float c = 0.f;
    if (j < D_LSTM) h_s[j] = 0.f;
    __syncthreads();

    float a_next = A[j];  // prefetch t=0

    for (int t = 0; t < T_LEN; ++t) {
        float a = a_next;
        if (t + 1 < T_LEN) a_next = A[(size_t)(t + 1) * 512 + j];  // hide L3/HBM latency

        // gates_pre[j] = a + h · w   (4 independent accumulator chains)
        const float4* h4 = (const float4*)h_s;
        float acc0 = 0.f, acc1 = 0.f, acc2 = 0.f, acc3 = 0.f;
        #pragma unroll
        for (int k4 = 0; k4 < D_LSTM/4; ++k4) {
            float4 hv = h4[k4];
            acc0 += w[4*k4+0] * hv.x;
            acc1 += w[4*k4+1] * hv.y;
            acc2 += w[4*k4+2] * hv.z;
            acc3 += w[4*k4+3] * hv.w;
        }
        gates_s[j] = a + ((acc0 + acc1) + (acc2 + acc3));
        __syncthreads();

        if (j < D_LSTM) {
            float gi = gates_s[j];
            float gf = gates_s[D_LSTM + j];
            float gg = gates_s[2*D_LSTM + j];
            float go = gates_s[3*D_LSTM + j];
            float si = sigmoid_f(gi);
            float sf = sigmoid_f(gf);
            float so = sigmoid_f(go);
            float tg = tanh_f(gg);
            c = sf * c + si * tg;
            h_s[j] = so * tanh_f(c);
        }
        __syncthreads();
    }

    // final FC: out = hT @ W_fc.T + b_fc
    if (j < N_CLS) {
        float acc = b_fc[j];
        #pragma unroll
        for (int k = 0; k < D_LSTM; ++k) acc += h_s[k] * W_fc[j * D_LSTM + k];
        out[j] = acc;
    }
}

// ---------------------------------------------------------------------------
extern "C" void kernel_launch(void* const* d_in, const int* in_sizes, int n_in,
                              void* d_out, int out_size, void* d_ws, size_t ws_size,
                              hipStream_t stream) {
    const float* x       = (const float*)d_in[0];
    const int*   esrc    = (const int*)  d_in[1];
    const int*   edst    = (const int*)  d_in[2];
    const float* W_rel1  = (const float*)d_in[3];
    const float* b_rel1  = (const float*)d_in[4];
    const float* W_root1 = (const float*)d_in[5];
    const float* W_rel2  = (const float*)d_in[6];
    const float* b_rel2  = (const float*)d_in[7];
    const float* W_root2 = (const float*)d_in[8];
    const float* W_ih    = (const float*)d_in[9];
    const float* W_hh    = (const float*)d_in[10];
    const float* b_ih    = (const float*)d_in[11];
    const float* b_hh    = (const float*)d_in[12];
    const float* W_fc    = (const float*)d_in[13];
    const float* b_fc    = (const float*)d_in[14];

    float* out = (float*)d_out;
    float* A   = (float*)d_ws;   // (T,512) f32 = 16 MB

    gnn_proj_kernel<<<T_LEN / TB, 64, 0, stream>>>(
        x, esrc, edst, W_rel1, b_rel1, W_root1,
        W_rel2, b_rel2, W_root2, W_ih, b_ih, b_hh, A);

    lstm_kernel<<<1, 512, 0, stream>>>(A, W_hh, W_fc, b_fc, out);
}